// Round 1
// baseline (1224.361 us; speedup 1.0000x reference)
//
#include <hip/hip_runtime.h>
#include <hip/hip_bf16.h>

// Problem: NGCFModel — U=256, I=1024, B=512, E=64
// out = (xui[512], gamma_u[512,64], gamma_i_i[512,64]) concatenated fp32.

#define U_CNT 256
#define I_CNT 1024
#define B_CNT 512
#define E_CNT 64
#define CMAX  528   // max distinct items (<=512) padded to mult of 8 + slack

// ---------------- Kernel A: histogram items, compact, user-present ----------
__global__ __launch_bounds__(1024) void setup_kernel(
    const int* __restrict__ users, const int* __restrict__ items,
    int* __restrict__ citems, float* __restrict__ ccnts,
    int* __restrict__ meta, int* __restrict__ upresent) {
  __shared__ int cnt[I_CNT];
  __shared__ int dcount;
  int tid = threadIdx.x;
  cnt[tid] = 0;
  if (tid == 0) dcount = 0;
  if (tid < U_CNT) upresent[tid] = 0;
  __syncthreads();
  if (tid < B_CNT) atomicAdd(&cnt[items[tid]], 1);
  __syncthreads();
  if (tid < B_CNT) upresent[users[tid]] = 1;  // ordered after zeroing by barrier
  int c = cnt[tid];
  if (c > 0) {
    int pos = atomicAdd(&dcount, 1);
    citems[pos] = tid;
    ccnts[pos]  = (float)c;
  }
  __syncthreads();
  int D = dcount;
  int Dpad = (D + 7) & ~7;
  if (tid >= D && tid < Dpad) { citems[tid] = 0; ccnts[tid] = 0.0f; }
  if (tid == 0) meta[0] = Dpad;
}

// ---------------- Kernel B: rs[u][i] = sum_d cnt_d * T[u, item_d, i] --------
// grid = 2*U blocks (user, half-row), 256 threads, float2/lane, unroll 8.
__global__ __launch_bounds__(256) void rowsum_kernel(
    const float* __restrict__ T, const int* __restrict__ citems,
    const float* __restrict__ ccnts, const int* __restrict__ meta,
    const int* __restrict__ upresent, float* __restrict__ rs) {
  int u    = blockIdx.x >> 1;
  int half = blockIdx.x & 1;
  if (!upresent[u]) return;  // block-uniform

  __shared__ int   s_items[CMAX];
  __shared__ float s_cnts[CMAX];
  int Dpad = meta[0];
  for (int i = threadIdx.x; i < Dpad; i += 256) {
    s_items[i] = citems[i];
    s_cnts[i]  = ccnts[i];
  }
  __syncthreads();

  const float2* Tu = (const float2*)(T + ((size_t)u << 20));  // u*1024*1024
  int col2 = half * 256 + threadIdx.x;  // float2 index in [0,512)
  float2 acc = make_float2(0.0f, 0.0f);

  for (int d = 0; d < Dpad; d += 8) {
    int   idx[8];
    float cf[8];
#pragma unroll
    for (int k = 0; k < 8; ++k) { idx[k] = s_items[d + k]; cf[k] = s_cnts[d + k]; }
    float2 t[8];
#pragma unroll
    for (int k = 0; k < 8; ++k) t[k] = Tu[(size_t)idx[k] * 512 + col2];
#pragma unroll
    for (int k = 0; k < 8; ++k) {
      acc.x = fmaf(cf[k], t[k].x, acc.x);
      acc.y = fmaf(cf[k], t[k].y, acc.y);
    }
  }
  ((float2*)(rs + ((size_t)u << 10)))[col2] = acc;
}

// ---------------- Kernel C: v_u = normalize( (rs_u gathered at items) @ gi )
__global__ __launch_bounds__(256) void gamma_kernel(
    const float* __restrict__ rs, const float* __restrict__ gi,
    const int* __restrict__ items, const int* __restrict__ upresent,
    float* __restrict__ vn) {
  int u = blockIdx.x;
  if (!upresent[u]) return;

  __shared__ float w[B_CNT];
  __shared__ float partial[4][E_CNT];
  int tid = threadIdx.x;
  const float* rsu = rs + ((size_t)u << 10);
  for (int j = tid; j < B_CNT; j += 256) w[j] = rsu[items[j]];
  __syncthreads();

  int e = tid & 63, q = tid >> 6;
  float acc = 0.0f;
  int j0 = q * 128;
#pragma unroll 4
  for (int j = j0; j < j0 + 128; ++j) acc = fmaf(w[j], gi[j * E_CNT + e], acc);
  partial[q][e] = acc;
  __syncthreads();

  if (q == 0) {  // wave 0
    float v = partial[0][e] + partial[1][e] + partial[2][e] + partial[3][e];
    float sq = v * v;
    for (int off = 32; off > 0; off >>= 1) sq += __shfl_down(sq, off);
    float n = __shfl(sq, 0);
    n = fmaxf(sqrtf(n), 1e-12f);
    vn[((size_t)u << 6) + e] = v / n;
  }
}

// ---------------- Kernel D: outputs -----------------------------------------
__global__ __launch_bounds__(64) void out_kernel(
    const float* __restrict__ gu, const int* __restrict__ users,
    const float* __restrict__ vn, float* __restrict__ out) {
  int b = blockIdx.x;
  int e = threadIdx.x;
  int u = users[b];
  float g  = gu[b * E_CNT + e];
  float vi = vn[((size_t)u << 6) + e];
  out[B_CNT + b * E_CNT + e] = g;                       // gamma_u
  out[B_CNT + B_CNT * E_CNT + b * E_CNT + e] = vi;      // gamma_i_i
  float p = g * vi;
  for (int off = 32; off > 0; off >>= 1) p += __shfl_down(p, off);
  if (e == 0) out[b] = p;                               // xui
}

extern "C" void kernel_launch(void* const* d_in, const int* in_sizes, int n_in,
                              void* d_out, int out_size, void* d_ws, size_t ws_size,
                              hipStream_t stream) {
  const float* T     = (const float*)d_in[0];
  const float* gu    = (const float*)d_in[1];
  const float* gi    = (const float*)d_in[2];
  const int*   users = (const int*)d_in[3];
  const int*   items = (const int*)d_in[4];
  float* out = (float*)d_out;

  // Workspace layout
  float* rs   = (float*)d_ws;                 // 256*1024
  float* vn   = rs + U_CNT * I_CNT;           // 256*64
  int*   citems = (int*)(vn + U_CNT * E_CNT); // CMAX
  float* ccnts  = (float*)(citems + CMAX);    // CMAX
  int*   meta   = (int*)(ccnts + CMAX);       // 8
  int*   upres  = meta + 8;                   // 256

  hipLaunchKernelGGL(setup_kernel, dim3(1), dim3(1024), 0, stream,
                     users, items, citems, ccnts, meta, upres);
  hipLaunchKernelGGL(rowsum_kernel, dim3(2 * U_CNT), dim3(256), 0, stream,
                     T, citems, ccnts, meta, upres, rs);
  hipLaunchKernelGGL(gamma_kernel, dim3(U_CNT), dim3(256), 0, stream,
                     rs, gi, items, upres, vn);
  hipLaunchKernelGGL(out_kernel, dim3(B_CNT), dim3(64), 0, stream,
                     gu, users, vn, out);
}